// Round 2
// baseline (167.040 us; speedup 1.0000x reference)
//
#include <hip/hip_runtime.h>
#include <stdint.h>

#define L_DIM 4096
#define D_DIM 512
#define H_DIM 256
#define T_DIM 8

typedef short bf16x8 __attribute__((ext_vector_type(8)));
typedef float f32x4 __attribute__((ext_vector_type(4)));

// ---------- helpers ----------
__device__ __forceinline__ unsigned short f2bf(float f) {
    union { float f; unsigned int u; } c; c.f = f;
    unsigned int u = c.u;
    unsigned int r = (u + 0x7fffu + ((u >> 16) & 1u)) >> 16;  // RNE
    return (unsigned short)r;
}

__device__ __forceinline__ float bits2f(unsigned int u) {
    union { unsigned int u; float f; } c; c.u = u; return c.f;
}

// unpack 4 bf16 (uint2) -> float4
__device__ __forceinline__ float4 unpack_bf4(uint2 q) {
    float4 r;
    r.x = bits2f(q.x << 16);
    r.y = bits2f(q.x & 0xffff0000u);
    r.z = bits2f(q.y << 16);
    r.w = bits2f(q.y & 0xffff0000u);
    return r;
}

__device__ __forceinline__ float wave_sum(float x) {
    #pragma unroll
    for (int off = 32; off > 0; off >>= 1) x += __shfl_xor(x, off, 64);
    return x;
}

__device__ __forceinline__ float dot4(float4 a, float4 b) {
    return a.x * b.x + a.y * b.y + a.z * b.z + a.w * b.w;
}

__device__ __forceinline__ float fast_tanh(float x) {
    float e = __expf(2.0f * x);
    return 1.0f - 2.0f / (e + 1.0f);
}

__device__ __forceinline__ float4 tanh4b(float4 a, float4 b) {
    float4 r;
    r.x = fast_tanh(a.x + b.x); r.y = fast_tanh(a.y + b.y);
    r.z = fast_tanh(a.z + b.z); r.w = fast_tanh(a.w + b.w);
    return r;
}

// ---------- K0: Ws (512x256 f32) -> WsT (256x512 bf16) ----------
__global__ void k_transpose_ws(const float* __restrict__ Ws,
                               unsigned short* __restrict__ WsT) {
    int idx = blockIdx.x * 256 + threadIdx.x;  // 0..131071
    int j = idx >> 9;        // H index
    int k = idx & 511;       // D index
    WsT[idx] = f2bf(Ws[k * H_DIM + j]);
}

// ---------- K1: v = emb @ Ws (bf16 out). M=32768 N=256 K=512 ----------
// BM=64, BN=256, BK=64. 512 threads = 8 waves (2m x 4n), wave tile 32x64.
// Double-buffered LDS (2 x 40KB), reg-staged prefetch. 2 blocks/CU.
__global__ __launch_bounds__(512, 4) void k_gemm_v(
    const float* __restrict__ emb,
    const unsigned short* __restrict__ WsT,
    unsigned short* __restrict__ v) {
    __shared__ __align__(16) char smem[81920];  // per buf: As 8KB, Bs 32KB

    const int tid  = threadIdx.x;
    const int lane = tid & 63;
    const int wid  = tid >> 6;
    const int wm   = wid >> 2;       // 0..1  (32-row half)
    const int wn   = wid & 3;        // 0..3  (64-col quarter)
    const long rowBase = (long)blockIdx.x * 64;

    // staging indices
    const int arow = tid >> 4, aq = tid & 15;       // A: 2 float4 per thread
    const int bj   = tid >> 3, bko = tid & 7;       // B: 4 uint4 per thread
    const float*          ag = emb + (rowBase + arow) * D_DIM + aq * 4;
    const unsigned short* bg = WsT + (long)bj * D_DIM + bko * 8;

    const int adst0 = arow * 128 + ((aq * 8) ^ ((arow & 7) << 4));
    const int adst1 = (arow + 32) * 128 + ((aq * 8) ^ (((arow + 32) & 7) << 4));
    const int bdst[4] = {
        bj * 128 + ((bko * 16) ^ ((bj & 7) << 4)),
        (bj + 64) * 128 + ((bko * 16) ^ (((bj + 64) & 7) << 4)),
        (bj + 128) * 128 + ((bko * 16) ^ (((bj + 128) & 7) << 4)),
        (bj + 192) * 128 + ((bko * 16) ^ (((bj + 192) & 7) << 4))};

    f32x4 acc[2][4];
    #pragma unroll
    for (int mi = 0; mi < 2; mi++)
        #pragma unroll
        for (int ni = 0; ni < 4; ni++) acc[mi][ni] = (f32x4){0.f, 0.f, 0.f, 0.f};

    // prologue: stage kt=0 into buf0
    {
        float4 a0 = *(const float4*)(ag);
        float4 a1 = *(const float4*)(ag + 32 * D_DIM);
        char* As = smem;
        char* Bs = smem + 8192;
        uint2 p0, p1;
        p0.x = (unsigned)f2bf(a0.x) | ((unsigned)f2bf(a0.y) << 16);
        p0.y = (unsigned)f2bf(a0.z) | ((unsigned)f2bf(a0.w) << 16);
        p1.x = (unsigned)f2bf(a1.x) | ((unsigned)f2bf(a1.y) << 16);
        p1.y = (unsigned)f2bf(a1.z) | ((unsigned)f2bf(a1.w) << 16);
        *(uint2*)(As + adst0) = p0;
        *(uint2*)(As + adst1) = p1;
        #pragma unroll
        for (int p = 0; p < 4; p++)
            *(uint4*)(Bs + bdst[p]) = *(const uint4*)(bg + (long)p * 64 * D_DIM);
    }
    __syncthreads();

    #pragma unroll
    for (int kt = 0; kt < 8; ++kt) {
        char* As = smem + (kt & 1) * 40960;
        char* Bs = As + 8192;
        char* Asn = smem + ((kt + 1) & 1) * 40960;
        char* Bsn = Asn + 8192;

        float4 a0, a1;
        uint4 b0, b1, b2, b3;
        if (kt < 7) {  // prefetch next tile into regs
            const float* ap = ag + (kt + 1) * 64;
            a0 = *(const float4*)(ap);
            a1 = *(const float4*)(ap + 32 * D_DIM);
            const unsigned short* bp = bg + (kt + 1) * 64;
            b0 = *(const uint4*)(bp);
            b1 = *(const uint4*)(bp + (long)64 * D_DIM);
            b2 = *(const uint4*)(bp + (long)128 * D_DIM);
            b3 = *(const uint4*)(bp + (long)192 * D_DIM);
        }

        // compute current buffer
        #pragma unroll
        for (int ks = 0; ks < 2; ++ks) {
            bf16x8 a[2], b[4];
            #pragma unroll
            for (int mi = 0; mi < 2; mi++) {
                int row = wm * 32 + mi * 16 + (lane & 15);
                a[mi] = *(const bf16x8*)(As + row * 128 +
                          (((ks * 64) + (lane >> 4) * 16) ^ ((row & 7) << 4)));
            }
            #pragma unroll
            for (int ni = 0; ni < 4; ni++) {
                int j = wn * 64 + ni * 16 + (lane & 15);
                b[ni] = *(const bf16x8*)(Bs + j * 128 +
                          (((ks * 64) + (lane >> 4) * 16) ^ ((j & 7) << 4)));
            }
            #pragma unroll
            for (int mi = 0; mi < 2; mi++)
                #pragma unroll
                for (int ni = 0; ni < 4; ni++)
                    acc[mi][ni] = __builtin_amdgcn_mfma_f32_16x16x32_bf16(
                        a[mi], b[ni], acc[mi][ni], 0, 0, 0);
        }

        if (kt < 7) {  // write prefetched tile to other buffer
            uint2 p0, p1;
            p0.x = (unsigned)f2bf(a0.x) | ((unsigned)f2bf(a0.y) << 16);
            p0.y = (unsigned)f2bf(a0.z) | ((unsigned)f2bf(a0.w) << 16);
            p1.x = (unsigned)f2bf(a1.x) | ((unsigned)f2bf(a1.y) << 16);
            p1.y = (unsigned)f2bf(a1.z) | ((unsigned)f2bf(a1.w) << 16);
            *(uint2*)(Asn + adst0) = p0;
            *(uint2*)(Asn + adst1) = p1;
            *(uint4*)(Bsn + bdst[0]) = b0;
            *(uint4*)(Bsn + bdst[1]) = b1;
            *(uint4*)(Bsn + bdst[2]) = b2;
            *(uint4*)(Bsn + bdst[3]) = b3;
        }
        __syncthreads();
    }

    // epilogue: C/D layout col=lane&15, row=(lane>>4)*4+reg  [m89-verified]
    #pragma unroll
    for (int mi = 0; mi < 2; mi++)
        #pragma unroll
        for (int ni = 0; ni < 4; ni++)
            #pragma unroll
            for (int r = 0; r < 4; r++) {
                long row = rowBase + wm * 32 + mi * 16 + (lane >> 4) * 4 + r;
                int  col = wn * 64 + ni * 16 + (lane & 15);
                v[row * H_DIM + col] = f2bf(acc[mi][ni][r]);
            }
}

// ---------- K2: recurrence. Parallel phase (p-dots, ga) + short chain ----------
__global__ __launch_bounds__(256) void k_seq(
    const float* __restrict__ emb, const float* __restrict__ rois,
    const float* __restrict__ Wx, const float* __restrict__ bx,
    const float* __restrict__ Wy, const float* __restrict__ by,
    const float* __restrict__ Wz, const float* __restrict__ bz,
    const float* __restrict__ bs, const float* __restrict__ Wh,
    const float* __restrict__ bh, const unsigned short* __restrict__ v,
    float* __restrict__ out) {
    const int lane = threadIdx.x & 63;
    const int l = blockIdx.x * 4 + (threadIdx.x >> 6);
    const int j4 = lane * 4;   // H slice (4 per lane)
    const int d8 = lane * 8;   // D slice (8 per lane)

    float4 Wh4 = *(const float4*)(Wh + (long)l * H_DIM + j4);
    float4 bs4 = *(const float4*)(bs + j4);
    float4 wx0 = *(const float4*)(Wx + (long)l * D_DIM + d8);
    float4 wx1 = *(const float4*)(Wx + (long)l * D_DIM + d8 + 4);
    float4 wy0 = *(const float4*)(Wy + (long)l * D_DIM + d8);
    float4 wy1 = *(const float4*)(Wy + (long)l * D_DIM + d8 + 4);
    float4 wz0 = *(const float4*)(Wz + (long)l * D_DIM + d8);
    float4 wz1 = *(const float4*)(Wz + (long)l * D_DIM + d8 + 4);
    float bxl = bx[l], byl = by[l], bzl = bz[l], bhl = bh[l];
    const float sx = 1.f / 767.f, sy = 1.f / 767.f, sz = 1.f / 575.f;

    // ---- parallel phase: p-dots and ga for all t (recurrence-independent) ----
    float px[T_DIM], py[T_DIM], pz[T_DIM], ga[T_DIM];
    uint2 vvp[T_DIM];
    #pragma unroll
    for (int t = 0; t < T_DIM; ++t) {
        const float* eb = emb + ((long)t * L_DIM + l) * D_DIM + d8;
        float4 f0 = *(const float4*)(eb);
        float4 f1 = *(const float4*)(eb + 4);
        px[t] = dot4(wx0, f0) + dot4(wx1, f1);
        py[t] = dot4(wy0, f0) + dot4(wy1, f1);
        pz[t] = dot4(wz0, f0) + dot4(wz1, f1);
        uint2 q = *(const uint2*)(v + ((long)t * L_DIM + l) * H_DIM + j4);
        vvp[t] = q;
        float4 sa = tanh4b(unpack_bf4(q), bs4);
        ga[t] = dot4(Wh4, sa);
    }
    #pragma unroll
    for (int t = 0; t < T_DIM; ++t) {
        px[t] = wave_sum(px[t]);
        py[t] = wave_sum(py[t]);
        pz[t] = wave_sum(pz[t]);
        ga[t] = wave_sum(ga[t]) + bhl;
    }

    // ---- t = 0 ----
    float4 u4 = unpack_bf4(vvp[0]);   // u0 = emb0 @ Ws
    float cx = rois[l * 3 + 0], cy = rois[l * 3 + 1], cz = rois[l * 3 + 2];
    float dx = px[0], dy = py[0], dz = pz[0];
    float prx = (dx + bxl) * sx + cx;
    float pry = (dy + byl) * sy + cy;
    float prz = (dz + bzl) * sz + cz;
    if (lane == 0) {
        out[l * 3 + 0] = prx; out[l * 3 + 1] = pry; out[l * 3 + 2] = prz;
    }

    // ---- t = 1..7: only gf's wave_sum is in the dependent chain ----
    #pragma unroll
    for (int t = 1; t < T_DIM; ++t) {
        float4 sf = tanh4b(u4, bs4);
        float gf = wave_sum(dot4(Wh4, sf)) + bhl;

        // softmax([gf,ga]) == (sigmoid(gf-ga), 1-...)
        float g0 = 1.0f / (1.0f + __expf(ga[t] - gf));
        float g1 = 1.0f - g0;

        float4 v4 = unpack_bf4(vvp[t]);
        u4.x = g0 * u4.x + g1 * v4.x; u4.y = g0 * u4.y + g1 * v4.y;
        u4.z = g0 * u4.z + g1 * v4.z; u4.w = g0 * u4.w + g1 * v4.w;

        // c uses OLD pred
        cx = cx * g0 + prx * g1; cy = cy * g0 + pry * g1; cz = cz * g0 + prz * g1;
        dx = g0 * dx + g1 * px[t]; dy = g0 * dy + g1 * py[t]; dz = g0 * dz + g1 * pz[t];

        prx = (dx + bxl) * sx + cx;
        pry = (dy + byl) * sy + cy;
        prz = (dz + bzl) * sz + cz;
        if (lane == 0) {
            float* o = out + (long)t * (L_DIM * 3) + l * 3;
            o[0] = prx; o[1] = pry; o[2] = prz;
        }
    }
}

// ---------- launch ----------
extern "C" void kernel_launch(void* const* d_in, const int* in_sizes, int n_in,
                              void* d_out, int out_size, void* d_ws, size_t ws_size,
                              hipStream_t stream) {
    const float* emb  = (const float*)d_in[0];
    const float* rois = (const float*)d_in[1];
    const float* Wx   = (const float*)d_in[2];
    const float* bx   = (const float*)d_in[3];
    const float* Wy   = (const float*)d_in[4];
    const float* by   = (const float*)d_in[5];
    const float* Wz   = (const float*)d_in[6];
    const float* bz   = (const float*)d_in[7];
    const float* Ws   = (const float*)d_in[8];
    const float* bs   = (const float*)d_in[9];
    const float* Wh   = (const float*)d_in[10];
    const float* bh   = (const float*)d_in[11];
    float* out = (float*)d_out;

    // workspace: v bf16 (32768x256x2B = 16MB) @0, WsT (256KB) after
    unsigned short* v   = (unsigned short*)d_ws;
    unsigned short* WsT = (unsigned short*)((char*)d_ws + (size_t)16 * 1024 * 1024);

    hipLaunchKernelGGL(k_transpose_ws, dim3(512), dim3(256), 0, stream, Ws, WsT);
    hipLaunchKernelGGL(k_gemm_v, dim3(512), dim3(512), 0, stream, emb, WsT, v);
    hipLaunchKernelGGL(k_seq, dim3(1024), dim3(256), 0, stream,
                       emb, rois, Wx, bx, Wy, by, Wz, bz, bs, Wh, bh, v, out);
}

// Round 3
// 153.799 us; speedup vs baseline: 1.0861x; 1.0861x over previous
//
#include <hip/hip_runtime.h>
#include <stdint.h>

#define L_DIM 4096
#define D_DIM 512
#define H_DIM 256
#define T_DIM 8

typedef short bf16x8 __attribute__((ext_vector_type(8)));
typedef float f32x4 __attribute__((ext_vector_type(4)));

// ---------- helpers ----------
__device__ __forceinline__ unsigned short f2bf(float f) {
    union { float f; unsigned int u; } c; c.f = f;
    unsigned int u = c.u;
    unsigned int r = (u + 0x7fffu + ((u >> 16) & 1u)) >> 16;  // RNE
    return (unsigned short)r;
}

__device__ __forceinline__ float bits2f(unsigned int u) {
    union { unsigned int u; float f; } c; c.u = u; return c.f;
}

__device__ __forceinline__ float4 unpack_bf4(uint2 q) {
    float4 r;
    r.x = bits2f(q.x << 16);
    r.y = bits2f(q.x & 0xffff0000u);
    r.z = bits2f(q.y << 16);
    r.w = bits2f(q.y & 0xffff0000u);
    return r;
}

__device__ __forceinline__ float wave_sum(float x) {
    #pragma unroll
    for (int off = 32; off > 0; off >>= 1) x += __shfl_xor(x, off, 64);
    return x;
}

__device__ __forceinline__ float dot4(float4 a, float4 b) {
    return a.x * b.x + a.y * b.y + a.z * b.z + a.w * b.w;
}

__device__ __forceinline__ float fast_tanh(float x) {
    float e = __expf(2.0f * x);
    return 1.0f - 2.0f / (e + 1.0f);
}

__device__ __forceinline__ float4 tanh4b(float4 a, float4 b) {
    float4 r;
    r.x = fast_tanh(a.x + b.x); r.y = fast_tanh(a.y + b.y);
    r.z = fast_tanh(a.z + b.z); r.w = fast_tanh(a.w + b.w);
    return r;
}

// ---------- K0: Ws (512x256 f32) -> WsT (256x512 bf16) ----------
__global__ void k_transpose_ws(const float* __restrict__ Ws,
                               unsigned short* __restrict__ WsT) {
    int idx = blockIdx.x * 256 + threadIdx.x;
    int j = idx >> 9;
    int k = idx & 511;
    WsT[idx] = f2bf(Ws[k * H_DIM + j]);
}

// ---------- K1: fused GEMM(64x256xK512) + recurrence, 8 l's per block ----------
// GEMM tile rows r=0..63 map to (t=r>>3, li=r&7), cols = full H=256.
// 512 threads = 8 waves (2m x 4n), wave tile 32x64. Double-buffered LDS 2x40KB.
// After GEMM: v -> LDS bf16 (32KB in dead buf0), one wave per l runs the chain.
__global__ __launch_bounds__(512, 4) void k_fused(
    const float* __restrict__ emb, const float* __restrict__ rois,
    const float* __restrict__ Wx, const float* __restrict__ bx,
    const float* __restrict__ Wy, const float* __restrict__ by,
    const float* __restrict__ Wz, const float* __restrict__ bz,
    const float* __restrict__ bs, const float* __restrict__ Wh,
    const float* __restrict__ bh, const unsigned short* __restrict__ WsT,
    float* __restrict__ out) {
    __shared__ __align__(16) char smem[81920];  // buf k: As 8KB + Bs 32KB @ k*40960

    const int tid  = threadIdx.x;
    const int lane = tid & 63;
    const int wid  = tid >> 6;
    const int wm   = wid >> 2;       // 0..1
    const int wn   = wid & 3;        // 0..3
    const int lbase = blockIdx.x * 8;

    // ---- A staging: rows arow (t0,li0) and arow+32 (t0+4,li0) ----
    const int arow = tid >> 4, aq = tid & 15;
    const int t0 = arow >> 3, li0 = arow & 7;
    const float* ag0 = emb + ((long)t0 * L_DIM + lbase + li0) * D_DIM + aq * 4;
    const float* ag1 = ag0 + (long)4 * L_DIM * D_DIM;   // t0+4, same li
    const int adst0 = arow * 128 + ((aq * 8) ^ ((arow & 7) << 4));
    const int adst1 = (arow + 32) * 128 + ((aq * 8) ^ (((arow + 32) & 7) << 4));
    // ---- B staging ----
    const int bj = tid >> 3, bko = tid & 7;
    const unsigned short* bg = WsT + (long)bj * D_DIM + bko * 8;
    const int bdst[4] = {
        bj * 128 + ((bko * 16) ^ ((bj & 7) << 4)),
        (bj + 64) * 128 + ((bko * 16) ^ (((bj + 64) & 7) << 4)),
        (bj + 128) * 128 + ((bko * 16) ^ (((bj + 128) & 7) << 4)),
        (bj + 192) * 128 + ((bko * 16) ^ (((bj + 192) & 7) << 4))};

    f32x4 acc[2][4];
    #pragma unroll
    for (int mi = 0; mi < 2; mi++)
        #pragma unroll
        for (int ni = 0; ni < 4; ni++) acc[mi][ni] = (f32x4){0.f, 0.f, 0.f, 0.f};

    // prologue: stage kt=0 into buf0
    {
        float4 a0 = *(const float4*)(ag0);
        float4 a1 = *(const float4*)(ag1);
        char* As = smem;
        char* Bs = smem + 8192;
        uint2 p0, p1;
        p0.x = (unsigned)f2bf(a0.x) | ((unsigned)f2bf(a0.y) << 16);
        p0.y = (unsigned)f2bf(a0.z) | ((unsigned)f2bf(a0.w) << 16);
        p1.x = (unsigned)f2bf(a1.x) | ((unsigned)f2bf(a1.y) << 16);
        p1.y = (unsigned)f2bf(a1.z) | ((unsigned)f2bf(a1.w) << 16);
        *(uint2*)(As + adst0) = p0;
        *(uint2*)(As + adst1) = p1;
        #pragma unroll
        for (int p = 0; p < 4; p++)
            *(uint4*)(Bs + bdst[p]) = *(const uint4*)(bg + (long)p * 64 * D_DIM);
    }
    __syncthreads();

    #pragma unroll
    for (int kt = 0; kt < 8; ++kt) {
        char* As = smem + (kt & 1) * 40960;
        char* Bs = As + 8192;
        char* Asn = smem + ((kt + 1) & 1) * 40960;
        char* Bsn = Asn + 8192;

        float4 a0, a1;
        uint4 b0, b1, b2, b3;
        if (kt < 7) {
            const float* ap0 = ag0 + (kt + 1) * 64;
            const float* ap1 = ag1 + (kt + 1) * 64;
            a0 = *(const float4*)(ap0);
            a1 = *(const float4*)(ap1);
            const unsigned short* bp = bg + (kt + 1) * 64;
            b0 = *(const uint4*)(bp);
            b1 = *(const uint4*)(bp + (long)64 * D_DIM);
            b2 = *(const uint4*)(bp + (long)128 * D_DIM);
            b3 = *(const uint4*)(bp + (long)192 * D_DIM);
        }

        #pragma unroll
        for (int ks = 0; ks < 2; ++ks) {
            bf16x8 a[2], b[4];
            #pragma unroll
            for (int mi = 0; mi < 2; mi++) {
                int row = wm * 32 + mi * 16 + (lane & 15);
                a[mi] = *(const bf16x8*)(As + row * 128 +
                          (((ks * 64) + (lane >> 4) * 16) ^ ((row & 7) << 4)));
            }
            #pragma unroll
            for (int ni = 0; ni < 4; ni++) {
                int j = wn * 64 + ni * 16 + (lane & 15);
                b[ni] = *(const bf16x8*)(Bs + j * 128 +
                          (((ks * 64) + (lane >> 4) * 16) ^ ((j & 7) << 4)));
            }
            #pragma unroll
            for (int mi = 0; mi < 2; mi++)
                #pragma unroll
                for (int ni = 0; ni < 4; ni++)
                    acc[mi][ni] = __builtin_amdgcn_mfma_f32_16x16x32_bf16(
                        a[mi], b[ni], acc[mi][ni], 0, 0, 0);
        }

        if (kt < 7) {
            uint2 p0, p1;
            p0.x = (unsigned)f2bf(a0.x) | ((unsigned)f2bf(a0.y) << 16);
            p0.y = (unsigned)f2bf(a0.z) | ((unsigned)f2bf(a0.w) << 16);
            p1.x = (unsigned)f2bf(a1.x) | ((unsigned)f2bf(a1.y) << 16);
            p1.y = (unsigned)f2bf(a1.z) | ((unsigned)f2bf(a1.w) << 16);
            *(uint2*)(Asn + adst0) = p0;
            *(uint2*)(Asn + adst1) = p1;
            *(uint4*)(Bsn + bdst[0]) = b0;
            *(uint4*)(Bsn + bdst[1]) = b1;
            *(uint4*)(Bsn + bdst[2]) = b2;
            *(uint4*)(Bsn + bdst[3]) = b3;
        }
        __syncthreads();
    }

    // ---- epilogue: acc -> v in LDS (bf16, 32KB, buf0 region is dead) ----
    // C/D layout: col=lane&15, row=(lane>>4)*4+reg  [m89-verified]
    unsigned short* v_lds = (unsigned short*)smem;   // [row=t*8+li][col] 64x256
    #pragma unroll
    for (int mi = 0; mi < 2; mi++)
        #pragma unroll
        for (int ni = 0; ni < 4; ni++)
            #pragma unroll
            for (int r = 0; r < 4; r++) {
                int row = wm * 32 + mi * 16 + (lane >> 4) * 4 + r;
                int col = wn * 64 + ni * 16 + (lane & 15);
                v_lds[row * H_DIM + col] = f2bf(acc[mi][ni][r]);
            }
    __syncthreads();

    // ---- recurrence: one wave per l ----
    const int l = lbase + wid;
    const int j4 = lane * 4;
    const int d8 = lane * 8;

    float4 Wh4 = *(const float4*)(Wh + (long)l * H_DIM + j4);
    float4 bs4 = *(const float4*)(bs + j4);
    float4 wx0 = *(const float4*)(Wx + (long)l * D_DIM + d8);
    float4 wx1 = *(const float4*)(Wx + (long)l * D_DIM + d8 + 4);
    float4 wy0 = *(const float4*)(Wy + (long)l * D_DIM + d8);
    float4 wy1 = *(const float4*)(Wy + (long)l * D_DIM + d8 + 4);
    float4 wz0 = *(const float4*)(Wz + (long)l * D_DIM + d8);
    float4 wz1 = *(const float4*)(Wz + (long)l * D_DIM + d8 + 4);
    float bxl = bx[l], byl = by[l], bzl = bz[l], bhl = bh[l];
    const float sx = 1.f / 767.f, sy = 1.f / 767.f, sz = 1.f / 575.f;

    uint2 vvp[T_DIM];
    #pragma unroll
    for (int t = 0; t < T_DIM; ++t)
        vvp[t] = *(const uint2*)(v_lds + (t * 8 + wid) * H_DIM + j4);

    // parallel phase: p-dots (emb re-read is block-local, L2-hot) and ga
    float px[T_DIM], py[T_DIM], pz[T_DIM], ga[T_DIM];
    #pragma unroll
    for (int t = 0; t < T_DIM; ++t) {
        const float* eb = emb + ((long)t * L_DIM + l) * D_DIM + d8;
        float4 f0 = *(const float4*)(eb);
        float4 f1 = *(const float4*)(eb + 4);
        px[t] = dot4(wx0, f0) + dot4(wx1, f1);
        py[t] = dot4(wy0, f0) + dot4(wy1, f1);
        pz[t] = dot4(wz0, f0) + dot4(wz1, f1);
        float4 sa = tanh4b(unpack_bf4(vvp[t]), bs4);
        ga[t] = dot4(Wh4, sa);
    }
    #pragma unroll
    for (int t = 0; t < T_DIM; ++t) {
        px[t] = wave_sum(px[t]);
        py[t] = wave_sum(py[t]);
        pz[t] = wave_sum(pz[t]);
        ga[t] = wave_sum(ga[t]) + bhl;
    }

    // t = 0
    float4 u4 = unpack_bf4(vvp[0]);
    float cx = rois[l * 3 + 0], cy = rois[l * 3 + 1], cz = rois[l * 3 + 2];
    float dx = px[0], dy = py[0], dz = pz[0];
    float prx = (dx + bxl) * sx + cx;
    float pry = (dy + byl) * sy + cy;
    float prz = (dz + bzl) * sz + cz;
    if (lane == 0) {
        out[l * 3 + 0] = prx; out[l * 3 + 1] = pry; out[l * 3 + 2] = prz;
    }

    // t = 1..7: only gf's wave_sum is in the dependent chain
    #pragma unroll
    for (int t = 1; t < T_DIM; ++t) {
        float4 sf = tanh4b(u4, bs4);
        float gf = wave_sum(dot4(Wh4, sf)) + bhl;

        float g0 = 1.0f / (1.0f + __expf(ga[t] - gf));
        float g1 = 1.0f - g0;

        float4 v4 = unpack_bf4(vvp[t]);
        u4.x = g0 * u4.x + g1 * v4.x; u4.y = g0 * u4.y + g1 * v4.y;
        u4.z = g0 * u4.z + g1 * v4.z; u4.w = g0 * u4.w + g1 * v4.w;

        cx = cx * g0 + prx * g1; cy = cy * g0 + pry * g1; cz = cz * g0 + prz * g1;
        dx = g0 * dx + g1 * px[t]; dy = g0 * dy + g1 * py[t]; dz = g0 * dz + g1 * pz[t];

        prx = (dx + bxl) * sx + cx;
        pry = (dy + byl) * sy + cy;
        prz = (dz + bzl) * sz + cz;
        if (lane == 0) {
            float* o = out + (long)t * (L_DIM * 3) + l * 3;
            o[0] = prx; o[1] = pry; o[2] = prz;
        }
    }
}

// ---------- launch ----------
extern "C" void kernel_launch(void* const* d_in, const int* in_sizes, int n_in,
                              void* d_out, int out_size, void* d_ws, size_t ws_size,
                              hipStream_t stream) {
    const float* emb  = (const float*)d_in[0];
    const float* rois = (const float*)d_in[1];
    const float* Wx   = (const float*)d_in[2];
    const float* bx   = (const float*)d_in[3];
    const float* Wy   = (const float*)d_in[4];
    const float* by   = (const float*)d_in[5];
    const float* Wz   = (const float*)d_in[6];
    const float* bz   = (const float*)d_in[7];
    const float* Ws   = (const float*)d_in[8];
    const float* bs   = (const float*)d_in[9];
    const float* Wh   = (const float*)d_in[10];
    const float* bh   = (const float*)d_in[11];
    float* out = (float*)d_out;

    unsigned short* WsT = (unsigned short*)d_ws;   // 256 KB

    hipLaunchKernelGGL(k_transpose_ws, dim3(512), dim3(256), 0, stream, Ws, WsT);
    hipLaunchKernelGGL(k_fused, dim3(512), dim3(512), 0, stream,
                       emb, rois, Wx, bx, Wy, by, Wz, bz, bs, Wh, bh, WsT, out);
}